// Round 7
// baseline (505.830 us; speedup 1.0000x reference)
//
#include <hip/hip_runtime.h>
#include <hip/hip_bf16.h>
#include <cstddef>

#define NN 10000      // nodes
#define EE0 160000    // raw edges (self-loops added on top)
#define NF 14
#define DC 256        // per-head channels

static inline int ceildiv(int a, int b) { return (a + b - 1) / b; }

__device__ __forceinline__ float lrelu02(float x) { return fmaxf(x, 0.2f * x); }

// round-to-nearest-even fp32 -> bf16 (as raw short)
__device__ __forceinline__ short f2bf(float f) {
    unsigned u = __float_as_uint(f);
    unsigned r = (u + 0x7FFFu + ((u >> 16) & 1u)) >> 16;
    return (short)r;
}
__device__ __forceinline__ float bf2f(short s) {
    return __uint_as_float(((unsigned)(unsigned short)s) << 16);
}

typedef __attribute__((ext_vector_type(8))) short bf16x8;
typedef __attribute__((ext_vector_type(4))) float f32x4;

#define GLDS(gaddr, laddr)                                                         \
    __builtin_amdgcn_global_load_lds(                                              \
        (__attribute__((address_space(1))) void*)(gaddr),                          \
        (__attribute__((address_space(3))) void*)(laddr), 16, 0, 0)

// ---------------- CSR build ----------------
__global__ void count_edges_k(const int* __restrict__ ei, int* __restrict__ counts,
                              int E0, int N) {
    int e = blockIdx.x * 256 + threadIdx.x;
    int E = E0 + N;
    if (e >= E) return;
    int dst = (e < E0) ? ei[E0 + e] : (e - E0);
    atomicAdd(&counts[dst], 1);
}

// 1024 threads; each scans a contiguous chunk; one 1024-wide LDS scan (10 steps).
__global__ __launch_bounds__(1024) void scan_k(const int* __restrict__ counts,
                                               int* __restrict__ row_off, int n) {
    __shared__ int sums[1024];
    int t = threadIdx.x;
    int chunk = (n + 1023) >> 10;
    int base = t * chunk;
    int lim = base + chunk; if (lim > n) lim = n;
    int s = 0;
    for (int i = base; i < lim; ++i) s += counts[i];
    sums[t] = s;
    __syncthreads();
    for (int off = 1; off < 1024; off <<= 1) {
        int v = (t >= off) ? sums[t - off] : 0;
        __syncthreads();
        sums[t] += v;
        __syncthreads();
    }
    int run = (t == 0) ? 0 : sums[t - 1];   // exclusive prefix of this chunk
    for (int i = base; i < lim; ++i) { run += counts[i]; row_off[i + 1] = run; }
    if (t == 0) row_off[0] = 0;
}

__global__ void scatter_k(const int* __restrict__ ei, const int* __restrict__ row_off,
                          int* __restrict__ cursor, int* __restrict__ csr_src,
                          int E0, int N) {
    int e = blockIdx.x * 256 + threadIdx.x;
    int E = E0 + N;
    if (e >= E) return;
    int src, dst;
    if (e < E0) { src = ei[e]; dst = ei[E0 + e]; }
    else        { src = dst = e - E0; }
    int pos = row_off[dst] + atomicAdd(&cursor[dst], 1);
    csr_src[pos] = src;
}

// ---------------- fused fp32 -> bf16 weight conversion (4 segments) ----------------
__global__ __launch_bounds__(256) void cvt_bf16_fused_k(
    const float* __restrict__ p0, short* __restrict__ q0, int n0,
    const float* __restrict__ p1, short* __restrict__ q1, int n1,
    const float* __restrict__ p2, short* __restrict__ q2, int n2,
    const float* __restrict__ p3, short* __restrict__ q3, int n3) {
    int i = blockIdx.x * 256 + threadIdx.x;
    const float* in; short* out; int idx;
    if (i < n0) { in = p0; out = q0; idx = i; }
    else if (i < n0 + n1) { in = p1; out = q1; idx = i - n0; }
    else if (i < n0 + n1 + n2) { in = p2; out = q2; idx = i - n0 - n1; }
    else if (i < n0 + n1 + n2 + n3) { in = p3; out = q3; idx = i - n0 - n1 - n2; }
    else return;
    float4 v = ((const float4*)in)[idx];
    short4 o;
    o.x = f2bf(v.x); o.y = f2bf(v.y); o.z = f2bf(v.z); o.w = f2bf(v.w);
    ((short4*)out)[idx] = o;
}

// ---------------- K-pad fp32 [rows,K] -> bf16 [rows,Kp] (zero tail), 3 segments ----
__global__ __launch_bounds__(256) void pad_bf16_k(
    const float* __restrict__ p0, short* __restrict__ q0, int r0,
    const float* __restrict__ p1, short* __restrict__ q1, int r1,
    const float* __restrict__ p2, short* __restrict__ q2, int r2,
    int K, int Kp) {
    int i = blockIdx.x * 256 + threadIdx.x;
    int rows = r0 + r1 + r2;
    int total = rows * Kp;
    if (i >= total) return;
    int row = i / Kp, col = i - row * Kp;
    const float* in; short* out; int r;
    if (row < r0) { in = p0; out = q0; r = row; }
    else if (row < r0 + r1) { in = p1; out = q1; r = row - r0; }
    else { in = p2; out = q2; r = row - r0 - r1; }
    out[(size_t)r * Kp + col] = (col < K) ? f2bf(in[(size_t)r * K + col]) : (short)0;
}

// ---------------- dual-output bf16 MFMA GEMM, XOR-swizzled LDS ----------------
__global__ __launch_bounds__(256) void gemm_bf16_dual(
    const short* __restrict__ A, const short* __restrict__ B,
    const float* __restrict__ b1, const float* __restrict__ b2,
    short* __restrict__ Cb, float* __restrict__ Cf,
    int M, int Nh, int Nf, int K) {
    __shared__ short As[128 * 32];
    __shared__ short Bs[128 * 32];
    const int t = threadIdx.x;
    const int wave = t >> 6, lane = t & 63;
    const int m0 = blockIdx.y * 128, n0 = blockIdx.x * 128;
    const int wm = (wave >> 1) * 64, wn = (wave & 1) * 64;
    const int lane15 = lane & 15, quad = lane >> 4;

    const int lrow = lane >> 2;                        // row within 16-row wave region
    const int lk = ((lane & 3) ^ ((lrow >> 1) & 3)) * 8;  // swizzled global k chunk
    int arow0 = m0 + wave * 16 + lrow;
    int arow1 = arow0 + 64;
    if (arow0 > M - 1) arow0 = M - 1;
    if (arow1 > M - 1) arow1 = M - 1;
    const short* ag0 = A + (size_t)arow0 * K + lk;
    const short* ag1 = A + (size_t)arow1 * K + lk;
    const short* bg0 = B + (size_t)(n0 + wave * 16 + lrow) * K + lk;
    const short* bg1 = B + (size_t)(n0 + 64 + wave * 16 + lrow) * K + lk;
    short* al0 = &As[(wave * 16) * 32];
    short* al1 = &As[(64 + wave * 16) * 32];
    short* bl0 = &Bs[(wave * 16) * 32];
    short* bl1 = &Bs[(64 + wave * 16) * 32];

    const int rql = (quad ^ ((lane15 >> 1) & 3)) * 8;  // swizzled read position

    f32x4 acc[4][4];
#pragma unroll
    for (int i = 0; i < 4; ++i)
#pragma unroll
        for (int j = 0; j < 4; ++j) acc[i][j] = (f32x4){0.f, 0.f, 0.f, 0.f};

    for (int k0 = 0; k0 < K; k0 += 32) {
        GLDS(ag0 + k0, al0);
        GLDS(ag1 + k0, al1);
        GLDS(bg0 + k0, bl0);
        GLDS(bg1 + k0, bl1);
        __syncthreads();
        bf16x8 af[4], bfr[4];
#pragma unroll
        for (int i = 0; i < 4; ++i)
            af[i] = *(const bf16x8*)&As[(wm + 16 * i + lane15) * 32 + rql];
#pragma unroll
        for (int j = 0; j < 4; ++j)
            bfr[j] = *(const bf16x8*)&Bs[(wn + 16 * j + lane15) * 32 + rql];
#pragma unroll
        for (int i = 0; i < 4; ++i)
#pragma unroll
            for (int j = 0; j < 4; ++j)
                acc[i][j] = __builtin_amdgcn_mfma_f32_16x16x32_bf16(
                    af[i], bfr[j], acc[i][j], 0, 0, 0);
        __syncthreads();
    }

    if (n0 >= Nh) {
#pragma unroll
        for (int j = 0; j < 4; ++j) {
            int nc = n0 - Nh + wn + 16 * j + lane15;
            float bias = b1[nc] + b2[nc];
#pragma unroll
            for (int i = 0; i < 4; ++i) {
                int mb = m0 + wm + 16 * i + quad * 4;
#pragma unroll
                for (int r = 0; r < 4; ++r) {
                    int m = mb + r;
                    if (m < M) Cf[(size_t)m * Nf + nc] = acc[i][j][r] + bias;
                }
            }
        }
    } else {
#pragma unroll
        for (int j = 0; j < 4; ++j) {
            int n = n0 + wn + 16 * j + lane15;
#pragma unroll
            for (int i = 0; i < 4; ++i) {
                int mb = m0 + wm + 16 * i + quad * 4;
#pragma unroll
                for (int r = 0; r < 4; ++r) {
                    int m = mb + r;
                    if (m < M) Cb[(size_t)m * Nh + n] = f2bf(acc[i][j][r]);
                }
            }
        }
    }
}

// ---------------- alpha_src/alpha_dst: [N,H] dot over C=256, bf16 h ----------------
__global__ __launch_bounds__(256) void alpha_k(
    const short* __restrict__ h, const float* __restrict__ a_s,
    const float* __restrict__ a_d, float* __restrict__ asrc,
    float* __restrict__ adst, int N, int H) {
    int wid = (int)((blockIdx.x * (size_t)blockDim.x + threadIdx.x) >> 6);
    int lane = threadIdx.x & 63;
    if (wid >= N * H) return;
    int n = wid / H, hh = wid - n * H;
    const short4 hv4 = *(const short4*)(h + (size_t)n * H * DC + hh * DC + lane * 4);
    const float4 sv = *(const float4*)(a_s + hh * DC + lane * 4);
    const float4 dv = *(const float4*)(a_d + hh * DC + lane * 4);
    float hx = bf2f(hv4.x), hy = bf2f(hv4.y), hz = bf2f(hv4.z), hw = bf2f(hv4.w);
    float s = hx * sv.x + hy * sv.y + hz * sv.z + hw * sv.w;
    float d = hx * dv.x + hy * dv.y + hz * dv.z + hw * dv.w;
#pragma unroll
    for (int off = 32; off > 0; off >>= 1) {
        s += __shfl_down(s, off);
        d += __shfl_down(d, off);
    }
    if (lane == 0) { asrc[wid] = s; adst[wid] = d; }
}

// ---------------- GAT aggregation, head-pair waves, fused lin-skip + ELU ----------
// one wave per (node, head-pair): lanes 0-31 = head 2p, lanes 32-63 = head 2p+1,
// each lane covers 8 channels via one 16B load per edge. H must be even.
__global__ __launch_bounds__(256) void gat_agg_pair(
    const short* __restrict__ hbuf, const float* __restrict__ lin,
    const float* __restrict__ asrc, const float* __restrict__ adst_a,
    const int* __restrict__ row_off, const int* __restrict__ csr_src,
    short* __restrict__ outx, int N, int H) {
    const int npair = H >> 1;
    int wid = (int)((blockIdx.x * (size_t)blockDim.x + threadIdx.x) >> 6);
    int lane = threadIdx.x & 63;
    if (wid >= N * npair) return;
    int n = wid / npair, p = wid - n * npair;
    int beg = row_off[n], end = row_off[n + 1];
    int deg = end - beg;
    int half = lane >> 5, sub = lane & 31;
    int head = 2 * p + half;
    float ad = adst_a[n * H + head];

    const size_t cbase = (size_t)n * (H * DC) + p * 512 + lane * 8;
    float acc[8];
    {
        const float* lp = lin + cbase;
        float4 l0 = *(const float4*)lp;
        float4 l1 = *(const float4*)(lp + 4);
        acc[0] = l0.x; acc[1] = l0.y; acc[2] = l0.z; acc[3] = l0.w;
        acc[4] = l1.x; acc[5] = l1.y; acc[6] = l1.z; acc[7] = l1.w;
    }

    if (deg <= 32) {
        int s = 0; float e = -1e38f;
        if (sub < deg) {
            s = csr_src[beg + sub];
            e = lrelu02(asrc[s * H + head] + ad);
        }
        float m = e;
#pragma unroll
        for (int off = 16; off > 0; off >>= 1) m = fmaxf(m, __shfl_xor(m, off));
        float pr = (sub < deg) ? __expf(e - m) : 0.f;
        float ds = pr;
#pragma unroll
        for (int off = 16; off > 0; off >>= 1) ds += __shfl_xor(ds, off);
        float coef = pr / (ds + 1e-16f);

        int i = 0;
        for (; i + 4 <= deg; i += 4) {
            bf16x8 v[4]; float wv[4];
#pragma unroll
            for (int u = 0; u < 4; ++u) {
                int su = __shfl(s, i + u);
                v[u] = *(const bf16x8*)(hbuf + (size_t)su * (H * DC) + p * 512 + lane * 8);
                wv[u] = __shfl(coef, (half << 5) + i + u);
            }
#pragma unroll
            for (int u = 0; u < 4; ++u)
#pragma unroll
                for (int c = 0; c < 8; ++c) acc[c] += wv[u] * bf2f(v[u][c]);
        }
        for (; i < deg; ++i) {
            int su = __shfl(s, i);
            float wv = __shfl(coef, (half << 5) + i);
            bf16x8 v = *(const bf16x8*)(hbuf + (size_t)su * (H * DC) + p * 512 + lane * 8);
#pragma unroll
            for (int c = 0; c < 8; ++c) acc[c] += wv * bf2f(v[c]);
        }
    } else {
        // strided half-wave softmax, serial payload (rare: P(deg>32) ~ 1e-4)
        float m = -1e38f;
        for (int i = beg + sub; i < end; i += 32) {
            int s = csr_src[i];
            m = fmaxf(m, lrelu02(asrc[s * H + head] + ad));
        }
#pragma unroll
        for (int off = 16; off > 0; off >>= 1) m = fmaxf(m, __shfl_xor(m, off));
        float ds = 0.f;
        for (int i = beg + sub; i < end; i += 32) {
            int s = csr_src[i];
            ds += __expf(lrelu02(asrc[s * H + head] + ad) - m);
        }
#pragma unroll
        for (int off = 16; off > 0; off >>= 1) ds += __shfl_xor(ds, off);
        float inv = 1.f / (ds + 1e-16f);
        for (int i = beg; i < end; ++i) {
            int s = csr_src[i];
            float wv = __expf(lrelu02(asrc[s * H + head] + ad) - m) * inv;
            bf16x8 v = *(const bf16x8*)(hbuf + (size_t)s * (H * DC) + p * 512 + lane * 8);
#pragma unroll
            for (int c = 0; c < 8; ++c) acc[c] += wv * bf2f(v[c]);
        }
    }
    // ELU + bf16 store (16B)
    bf16x8 o;
#pragma unroll
    for (int c = 0; c < 8; ++c) {
        float a = acc[c];
        a = a > 0.f ? a : __expf(a) - 1.f;
        o[c] = f2bf(a);
    }
    *(bf16x8*)(outx + cbase) = o;
}

// ---------------- Layer-3 aggregation: mean over 6 heads, write d_out[N,256] -------
// one wave per node; per edge 3 x 16B loads cover all 6 heads (head = 2j + lane/32);
// cross-half shfl_xor(32) merges even/odd head sums. out preloaded with lin3+b3+lb3.
__global__ __launch_bounds__(256) void gat_agg_mean(
    const short* __restrict__ hbuf, const float* __restrict__ asrc,
    const float* __restrict__ adst_a, const int* __restrict__ row_off,
    const int* __restrict__ csr_src, float* __restrict__ out, int N) {
    const int H = 6;
    int wid = (int)((blockIdx.x * (size_t)blockDim.x + threadIdx.x) >> 6);
    int lane = threadIdx.x & 63;
    if (wid >= N) return;
    int n = wid;
    int beg = row_off[n], end = row_off[n + 1];
    int deg = end - beg;
    int half = lane >> 5, sub = lane & 31;
    const float invH = 1.f / 6.f;

    float acc[8];
#pragma unroll
    for (int c = 0; c < 8; ++c) acc[c] = 0.f;

    if (deg <= 64) {
        int s = 0;
        float as6[6];
        if (lane < deg) {
            s = csr_src[beg + lane];
            const float2* ap = (const float2*)(asrc + (size_t)s * H);
            float2 v0 = ap[0], v1 = ap[1], v2 = ap[2];
            as6[0] = v0.x; as6[1] = v0.y; as6[2] = v1.x;
            as6[3] = v1.y; as6[4] = v2.x; as6[5] = v2.y;
        }
        float coefh[6];
#pragma unroll
        for (int hh = 0; hh < 6; ++hh) {
            float ad = adst_a[n * H + hh];
            float e = (lane < deg) ? lrelu02(as6[hh] + ad) : -1e38f;
            float m = e;
#pragma unroll
            for (int off = 32; off > 0; off >>= 1) m = fmaxf(m, __shfl_xor(m, off));
            float pv = (lane < deg) ? __expf(e - m) : 0.f;
            float dsum = pv;
#pragma unroll
            for (int off = 32; off > 0; off >>= 1) dsum += __shfl_xor(dsum, off);
            coefh[hh] = pv * invH / (dsum + 1e-16f);
        }
        int i = 0;
        for (; i + 2 <= deg; i += 2) {
            int sa = __shfl(s, i), sb = __shfl(s, i + 1);
            const short* ba = hbuf + (size_t)sa * (H * DC) + lane * 8;
            const short* bb = hbuf + (size_t)sb * (H * DC) + lane * 8;
            bf16x8 va[3], vb[3];
#pragma unroll
            for (int j = 0; j < 3; ++j) {
                va[j] = *(const bf16x8*)(ba + j * 512);
                vb[j] = *(const bf16x8*)(bb + j * 512);
            }
#pragma unroll
            for (int j = 0; j < 3; ++j) {
                float wa0 = __shfl(coefh[2 * j], i), wa1 = __shfl(coefh[2 * j + 1], i);
                float wb0 = __shfl(coefh[2 * j], i + 1), wb1 = __shfl(coefh[2 * j + 1], i + 1);
                float wA = half ? wa1 : wa0;
                float wB = half ? wb1 : wb0;
#pragma unroll
                for (int c = 0; c < 8; ++c)
                    acc[c] += wA * bf2f(va[j][c]) + wB * bf2f(vb[j][c]);
            }
        }
        if (i < deg) {
            int si = __shfl(s, i);
            const short* bi = hbuf + (size_t)si * (H * DC) + lane * 8;
#pragma unroll
            for (int j = 0; j < 3; ++j) {
                bf16x8 v = *(const bf16x8*)(bi + j * 512);
                float w0 = __shfl(coefh[2 * j], i), w1 = __shfl(coefh[2 * j + 1], i);
                float wv = half ? w1 : w0;
#pragma unroll
                for (int c = 0; c < 8; ++c) acc[c] += wv * bf2f(v[c]);
            }
        }
    } else {
        // rare fallback: per-head broadcast m/inv, serial edges, on-the-fly coef
        float m6[6], inv6[6], ad6[6];
#pragma unroll
        for (int hh = 0; hh < 6; ++hh) ad6[hh] = adst_a[n * H + hh];
        for (int hh = 0; hh < 6; ++hh) {
            float m = -1e38f;
            for (int i = beg + lane; i < end; i += 64) {
                int s = csr_src[i];
                m = fmaxf(m, lrelu02(asrc[s * H + hh] + ad6[hh]));
            }
#pragma unroll
            for (int off = 32; off > 0; off >>= 1) m = fmaxf(m, __shfl_xor(m, off));
            float ds = 0.f;
            for (int i = beg + lane; i < end; i += 64) {
                int s = csr_src[i];
                ds += __expf(lrelu02(asrc[s * H + hh] + ad6[hh]) - m);
            }
#pragma unroll
            for (int off = 32; off > 0; off >>= 1) ds += __shfl_xor(ds, off);
            m6[hh] = m;
            inv6[hh] = invH / (ds + 1e-16f);
        }
        for (int i = beg; i < end; ++i) {
            int s = csr_src[i];
            const short* bi = hbuf + (size_t)s * (H * DC) + lane * 8;
#pragma unroll
            for (int j = 0; j < 3; ++j) {
                int h = 2 * j + half;
                float wv = __expf(lrelu02(asrc[s * H + h] + ad6[h]) - m6[h]) * inv6[h];
                bf16x8 v = *(const bf16x8*)(bi + j * 512);
#pragma unroll
                for (int c = 0; c < 8; ++c) acc[c] += wv * bf2f(v[c]);
            }
        }
    }
    // merge even/odd-head halves, add lin (already in out), store
#pragma unroll
    for (int c = 0; c < 8; ++c) acc[c] += __shfl_xor(acc[c], 32);
    if (lane < 32) {
        float* op = out + (size_t)n * DC + sub * 8;
        float4 o0 = *(float4*)op;
        float4 o1 = *(float4*)(op + 4);
        o0.x += acc[0]; o0.y += acc[1]; o0.z += acc[2]; o0.w += acc[3];
        o1.x += acc[4]; o1.y += acc[5]; o1.z += acc[6]; o1.w += acc[7];
        *(float4*)op = o0;
        *(float4*)(op + 4) = o1;
    }
}

// ---------------- launch ----------------
extern "C" void kernel_launch(void* const* d_in, const int* in_sizes, int n_in,
                              void* d_out, int out_size, void* d_ws, size_t ws_size,
                              hipStream_t stream) {
    const float* x   = (const float*)d_in[0];
    const int*   ei  = (const int*)d_in[1];
    const float* W1  = (const float*)d_in[2];
    const float* a1s = (const float*)d_in[3];
    const float* a1d = (const float*)d_in[4];
    const float* b1  = (const float*)d_in[5];
    const float* lw1 = (const float*)d_in[6];
    const float* lb1 = (const float*)d_in[7];
    const float* W2  = (const float*)d_in[8];
    const float* a2s = (const float*)d_in[9];
    const float* a2d = (const float*)d_in[10];
    const float* b2  = (const float*)d_in[11];
    const float* lw2 = (const float*)d_in[12];
    const float* lb2 = (const float*)d_in[13];
    const float* W3  = (const float*)d_in[14];
    const float* a3s = (const float*)d_in[15];
    const float* a3d = (const float*)d_in[16];
    const float* b3  = (const float*)d_in[17];
    const float* lw3 = (const float*)d_in[18];
    const float* lb3 = (const float*)d_in[19];
    float* out = (float*)d_out;

    const int N = NN, E0 = EE0, E = EE0 + NN;

    unsigned char* w = (unsigned char*)d_ws;
    size_t off = 0;
    auto alloc = [&](size_t bytes) {
        void* p = w + off;
        off += (bytes + 255) & ~(size_t)255;
        return p;
    };
    short* hbuf   = (short*)alloc((size_t)N * 1536 * 2);  // h bf16 (max: layer 3)
    float* buf    = (float*)alloc((size_t)N * 1024 * 4);  // lin1, then lin2 (fp32)
    short* xb     = (short*)alloc((size_t)N * 1024 * 2);  // x1 bf16, then x2 bf16
    short* xpad   = (short*)alloc((size_t)N * 32 * 2);    // x zero-padded K=32 bf16
    short* W1p    = (short*)alloc((size_t)1024 * 32 * 2);       // + lw1p right after
    short* lw1p   = (short*)alloc((size_t)1024 * 32 * 2);
    short* W2b    = (short*)alloc((size_t)1024 * 1024 * 2);     // + lw2b right after
    short* lw2b   = (short*)alloc((size_t)1024 * 1024 * 2);
    short* W3b    = (short*)alloc((size_t)1536 * 1024 * 2);     // + lw3b right after
    short* lw3b   = (short*)alloc((size_t)256 * 1024 * 2);
    float* asrc   = (float*)alloc((size_t)N * 6 * 4);
    float* adst   = (float*)alloc((size_t)N * 6 * 4);
    int* row_off  = (int*)alloc((size_t)(N + 1) * 4);
    int* counts2  = (int*)alloc((size_t)2 * N * 4);  // counts | cursor
    int* counts   = counts2;
    int* cursor   = counts2 + N;
    int* csr_src  = (int*)alloc((size_t)E * 4);
    (void)ws_size; (void)n_in; (void)in_sizes; (void)out_size;

    // ---- CSR build ----
    hipMemsetAsync(counts2, 0, (size_t)2 * N * 4, stream);
    count_edges_k<<<ceildiv(E, 256), 256, 0, stream>>>(ei, counts, E0, N);
    scan_k<<<1, 1024, 0, stream>>>(counts, row_off, N);
    scatter_k<<<ceildiv(E, 256), 256, 0, stream>>>(ei, row_off, cursor, csr_src, E0, N);

    // ---- weight bf16 conversion (fused) + K-pad for layer 1 ----
    {
        int q0 = 1024 * 1024 / 4, q1 = 1024 * 1024 / 4, q2 = 1536 * 1024 / 4,
            q3 = 256 * 1024 / 4;
        cvt_bf16_fused_k<<<ceildiv(q0 + q1 + q2 + q3, 256), 256, 0, stream>>>(
            W2, W2b, q0, lw2, lw2b, q1, W3, W3b, q2, lw3, lw3b, q3);
        int rows = N + 1024 + 1024;
        pad_bf16_k<<<ceildiv(rows * 32, 256), 256, 0, stream>>>(
            x, xpad, N, W1, W1p, 1024, lw1, lw1p, 1024, NF, 32);
    }

    // ---- Layer 1 (H=4, K=14 padded to 32): h->hbuf bf16, lin->buf fp32 ----
    gemm_bf16_dual<<<dim3(16, ceildiv(N, 128)), 256, 0, stream>>>(
        xpad, W1p, b1, lb1, hbuf, buf, N, 1024, 1024, 32);
    alpha_k<<<ceildiv(N * 4, 4), 256, 0, stream>>>(hbuf, a1s, a1d, asrc, adst, N, 4);
    gat_agg_pair<<<ceildiv(N * 2, 4), 256, 0, stream>>>(hbuf, buf, asrc, adst, row_off,
                                                        csr_src, xb, N, 4);

    // ---- Layer 2 (H=4, K=1024) ----
    gemm_bf16_dual<<<dim3(16, ceildiv(N, 128)), 256, 0, stream>>>(
        xb, W2b, b2, lb2, hbuf, buf, N, 1024, 1024, 1024);
    alpha_k<<<ceildiv(N * 4, 4), 256, 0, stream>>>(hbuf, a2s, a2d, asrc, adst, N, 4);
    gat_agg_pair<<<ceildiv(N * 2, 4), 256, 0, stream>>>(hbuf, buf, asrc, adst, row_off,
                                                        csr_src, xb, N, 4);

    // ---- Layer 3 (H=6, K=1024, mean heads): h->hbuf, lin->out fp32 ----
    gemm_bf16_dual<<<dim3(14, ceildiv(N, 128)), 256, 0, stream>>>(
        xb, W3b, b3, lb3, hbuf, out, N, 1536, 256, 1024);
    alpha_k<<<ceildiv(N * 6, 4), 256, 0, stream>>>(hbuf, a3s, a3d, asrc, adst, N, 6);
    gat_agg_mean<<<ceildiv(N, 4), 256, 0, stream>>>(hbuf, asrc, adst, row_off, csr_src,
                                                    out, N);
}

// Round 8
// 482.643 us; speedup vs baseline: 1.0480x; 1.0480x over previous
//
#include <hip/hip_runtime.h>
#include <hip/hip_bf16.h>
#include <cstddef>

#define NN 10000      // nodes
#define EE0 160000    // raw edges (self-loops added on top)
#define NF 14
#define DC 256        // per-head channels

static inline int ceildiv(int a, int b) { return (a + b - 1) / b; }

__device__ __forceinline__ float lrelu02(float x) { return fmaxf(x, 0.2f * x); }

// round-to-nearest-even fp32 -> bf16 (as raw short)
__device__ __forceinline__ short f2bf(float f) {
    unsigned u = __float_as_uint(f);
    unsigned r = (u + 0x7FFFu + ((u >> 16) & 1u)) >> 16;
    return (short)r;
}
__device__ __forceinline__ float bf2f(short s) {
    return __uint_as_float(((unsigned)(unsigned short)s) << 16);
}

typedef __attribute__((ext_vector_type(8))) short bf16x8;
typedef __attribute__((ext_vector_type(4))) float f32x4;

#define GLDS(gaddr, laddr)                                                         \
    __builtin_amdgcn_global_load_lds(                                              \
        (__attribute__((address_space(1))) void*)(gaddr),                          \
        (__attribute__((address_space(3))) void*)(laddr), 16, 0, 0)

// ---------------- CSR build ----------------
__global__ void count_edges_k(const int* __restrict__ ei, int* __restrict__ counts,
                              int E0, int N) {
    int e = blockIdx.x * 256 + threadIdx.x;
    int E = E0 + N;
    if (e >= E) return;
    int dst = (e < E0) ? ei[E0 + e] : (e - E0);
    atomicAdd(&counts[dst], 1);
}

// 1024 threads; each scans a contiguous chunk; one 1024-wide LDS scan (10 steps).
__global__ __launch_bounds__(1024) void scan_k(const int* __restrict__ counts,
                                               int* __restrict__ row_off, int n) {
    __shared__ int sums[1024];
    int t = threadIdx.x;
    int chunk = (n + 1023) >> 10;
    int base = t * chunk;
    int lim = base + chunk; if (lim > n) lim = n;
    int s = 0;
    for (int i = base; i < lim; ++i) s += counts[i];
    sums[t] = s;
    __syncthreads();
    for (int off = 1; off < 1024; off <<= 1) {
        int v = (t >= off) ? sums[t - off] : 0;
        __syncthreads();
        sums[t] += v;
        __syncthreads();
    }
    int run = (t == 0) ? 0 : sums[t - 1];   // exclusive prefix of this chunk
    for (int i = base; i < lim; ++i) { run += counts[i]; row_off[i + 1] = run; }
    if (t == 0) row_off[0] = 0;
}

__global__ void scatter_k(const int* __restrict__ ei, const int* __restrict__ row_off,
                          int* __restrict__ cursor, int* __restrict__ csr_src,
                          int E0, int N) {
    int e = blockIdx.x * 256 + threadIdx.x;
    int E = E0 + N;
    if (e >= E) return;
    int src, dst;
    if (e < E0) { src = ei[e]; dst = ei[E0 + e]; }
    else        { src = dst = e - E0; }
    int pos = row_off[dst] + atomicAdd(&cursor[dst], 1);
    csr_src[pos] = src;
}

// ---------------- fused fp32 -> bf16 weight conversion (4 segments) ----------------
__global__ __launch_bounds__(256) void cvt_bf16_fused_k(
    const float* __restrict__ p0, short* __restrict__ q0, int n0,
    const float* __restrict__ p1, short* __restrict__ q1, int n1,
    const float* __restrict__ p2, short* __restrict__ q2, int n2,
    const float* __restrict__ p3, short* __restrict__ q3, int n3) {
    int i = blockIdx.x * 256 + threadIdx.x;
    const float* in; short* out; int idx;
    if (i < n0) { in = p0; out = q0; idx = i; }
    else if (i < n0 + n1) { in = p1; out = q1; idx = i - n0; }
    else if (i < n0 + n1 + n2) { in = p2; out = q2; idx = i - n0 - n1; }
    else if (i < n0 + n1 + n2 + n3) { in = p3; out = q3; idx = i - n0 - n1 - n2; }
    else return;
    float4 v = ((const float4*)in)[idx];
    short4 o;
    o.x = f2bf(v.x); o.y = f2bf(v.y); o.z = f2bf(v.z); o.w = f2bf(v.w);
    ((short4*)out)[idx] = o;
}

// ---------------- K-pad fp32 [rows,K] -> bf16 [rows,Kp] (zero tail), 3 segments ----
__global__ __launch_bounds__(256) void pad_bf16_k(
    const float* __restrict__ p0, short* __restrict__ q0, int r0,
    const float* __restrict__ p1, short* __restrict__ q1, int r1,
    const float* __restrict__ p2, short* __restrict__ q2, int r2,
    int K, int Kp) {
    int i = blockIdx.x * 256 + threadIdx.x;
    int rows = r0 + r1 + r2;
    int total = rows * Kp;
    if (i >= total) return;
    int row = i / Kp, col = i - row * Kp;
    const float* in; short* out; int r;
    if (row < r0) { in = p0; out = q0; r = row; }
    else if (row < r0 + r1) { in = p1; out = q1; r = row - r0; }
    else { in = p2; out = q2; r = row - r0 - r1; }
    out[(size_t)r * Kp + col] = (col < K) ? f2bf(in[(size_t)r * K + col]) : (short)0;
}

// ---------------- dual-output bf16 MFMA GEMM, XOR-swizzled LDS ----------------
__global__ __launch_bounds__(256) void gemm_bf16_dual(
    const short* __restrict__ A, const short* __restrict__ B,
    const float* __restrict__ b1, const float* __restrict__ b2,
    short* __restrict__ Cb, float* __restrict__ Cf,
    int M, int Nh, int Nf, int K) {
    __shared__ short As[128 * 32];
    __shared__ short Bs[128 * 32];
    const int t = threadIdx.x;
    const int wave = t >> 6, lane = t & 63;
    const int m0 = blockIdx.y * 128, n0 = blockIdx.x * 128;
    const int wm = (wave >> 1) * 64, wn = (wave & 1) * 64;
    const int lane15 = lane & 15, quad = lane >> 4;

    const int lrow = lane >> 2;                        // row within 16-row wave region
    const int lk = ((lane & 3) ^ ((lrow >> 1) & 3)) * 8;  // swizzled global k chunk
    int arow0 = m0 + wave * 16 + lrow;
    int arow1 = arow0 + 64;
    if (arow0 > M - 1) arow0 = M - 1;
    if (arow1 > M - 1) arow1 = M - 1;
    const short* ag0 = A + (size_t)arow0 * K + lk;
    const short* ag1 = A + (size_t)arow1 * K + lk;
    const short* bg0 = B + (size_t)(n0 + wave * 16 + lrow) * K + lk;
    const short* bg1 = B + (size_t)(n0 + 64 + wave * 16 + lrow) * K + lk;
    short* al0 = &As[(wave * 16) * 32];
    short* al1 = &As[(64 + wave * 16) * 32];
    short* bl0 = &Bs[(wave * 16) * 32];
    short* bl1 = &Bs[(64 + wave * 16) * 32];

    const int rql = (quad ^ ((lane15 >> 1) & 3)) * 8;  // swizzled read position

    f32x4 acc[4][4];
#pragma unroll
    for (int i = 0; i < 4; ++i)
#pragma unroll
        for (int j = 0; j < 4; ++j) acc[i][j] = (f32x4){0.f, 0.f, 0.f, 0.f};

    for (int k0 = 0; k0 < K; k0 += 32) {
        GLDS(ag0 + k0, al0);
        GLDS(ag1 + k0, al1);
        GLDS(bg0 + k0, bl0);
        GLDS(bg1 + k0, bl1);
        __syncthreads();
        bf16x8 af[4], bfr[4];
#pragma unroll
        for (int i = 0; i < 4; ++i)
            af[i] = *(const bf16x8*)&As[(wm + 16 * i + lane15) * 32 + rql];
#pragma unroll
        for (int j = 0; j < 4; ++j)
            bfr[j] = *(const bf16x8*)&Bs[(wn + 16 * j + lane15) * 32 + rql];
#pragma unroll
        for (int i = 0; i < 4; ++i)
#pragma unroll
            for (int j = 0; j < 4; ++j)
                acc[i][j] = __builtin_amdgcn_mfma_f32_16x16x32_bf16(
                    af[i], bfr[j], acc[i][j], 0, 0, 0);
        __syncthreads();
    }

    if (n0 >= Nh) {
#pragma unroll
        for (int j = 0; j < 4; ++j) {
            int nc = n0 - Nh + wn + 16 * j + lane15;
            float bias = b1[nc] + b2[nc];
#pragma unroll
            for (int i = 0; i < 4; ++i) {
                int mb = m0 + wm + 16 * i + quad * 4;
#pragma unroll
                for (int r = 0; r < 4; ++r) {
                    int m = mb + r;
                    if (m < M) Cf[(size_t)m * Nf + nc] = acc[i][j][r] + bias;
                }
            }
        }
    } else {
#pragma unroll
        for (int j = 0; j < 4; ++j) {
            int n = n0 + wn + 16 * j + lane15;
#pragma unroll
            for (int i = 0; i < 4; ++i) {
                int mb = m0 + wm + 16 * i + quad * 4;
#pragma unroll
                for (int r = 0; r < 4; ++r) {
                    int m = mb + r;
                    if (m < M) Cb[(size_t)m * Nh + n] = f2bf(acc[i][j][r]);
                }
            }
        }
    }
}

// ---------------- alpha_src/alpha_dst: [N,H] dot over C=256, bf16 h ----------------
__global__ __launch_bounds__(256) void alpha_k(
    const short* __restrict__ h, const float* __restrict__ a_s,
    const float* __restrict__ a_d, float* __restrict__ asrc,
    float* __restrict__ adst, int N, int H) {
    int wid = (int)((blockIdx.x * (size_t)blockDim.x + threadIdx.x) >> 6);
    int lane = threadIdx.x & 63;
    if (wid >= N * H) return;
    int n = wid / H, hh = wid - n * H;
    const short4 hv4 = *(const short4*)(h + (size_t)n * H * DC + hh * DC + lane * 4);
    const float4 sv = *(const float4*)(a_s + hh * DC + lane * 4);
    const float4 dv = *(const float4*)(a_d + hh * DC + lane * 4);
    float hx = bf2f(hv4.x), hy = bf2f(hv4.y), hz = bf2f(hv4.z), hw = bf2f(hv4.w);
    float s = hx * sv.x + hy * sv.y + hz * sv.z + hw * sv.w;
    float d = hx * dv.x + hy * dv.y + hz * dv.z + hw * dv.w;
#pragma unroll
    for (int off = 32; off > 0; off >>= 1) {
        s += __shfl_down(s, off);
        d += __shfl_down(d, off);
    }
    if (lane == 0) { asrc[wid] = s; adst[wid] = d; }
}

// ---------------- GAT aggregation, concat heads, fused lin-skip + ELU, bf16 out ----
// one wave per (node, head); fast path deg<=64 keeps edges in registers;
// edge loop unrolled x8 for load-level parallelism. (R6 version — 490us config)
__global__ __launch_bounds__(256) void gat_agg(
    const short* __restrict__ hbuf, const float* __restrict__ lin,
    const float* __restrict__ asrc, const float* __restrict__ adst_a,
    const int* __restrict__ row_off, const int* __restrict__ csr_src,
    short* __restrict__ outx, int N, int H) {
    int wid = (int)((blockIdx.x * (size_t)blockDim.x + threadIdx.x) >> 6);
    int lane = threadIdx.x & 63;
    if (wid >= N * H) return;
    int n = wid / H, hh = wid - n * H;
    int beg = row_off[n], end = row_off[n + 1];
    int deg = end - beg;
    float ad = adst_a[wid];

    size_t cbase = (size_t)n * H * DC + hh * DC + lane * 4;
    float4 acc = *(const float4*)(lin + cbase);

    if (deg <= 64) {
        int s = 0; float e = -1e38f;
        if (lane < deg) {
            s = csr_src[beg + lane];
            e = lrelu02(asrc[s * H + hh] + ad);
        }
        float m = e;
#pragma unroll
        for (int off = 32; off > 0; off >>= 1) m = fmaxf(m, __shfl_xor(m, off));
        float p = (lane < deg) ? __expf(e - m) : 0.f;
        float dsum = p;
#pragma unroll
        for (int off = 32; off > 0; off >>= 1) dsum += __shfl_xor(dsum, off);
        float coef = p / (dsum + 1e-16f);

        const size_t hoff = (size_t)hh * DC + lane * 4;
        int i = 0;
        for (; i + 8 <= deg; i += 8) {
            short4 v[8]; float wv[8];
#pragma unroll
            for (int u = 0; u < 8; ++u) {
                int su = __shfl(s, i + u);
                v[u] = *(const short4*)(hbuf + (size_t)su * (H * DC) + hoff);
                wv[u] = __shfl(coef, i + u);
            }
#pragma unroll
            for (int u = 0; u < 8; ++u) {
                acc.x += wv[u] * bf2f(v[u].x);
                acc.y += wv[u] * bf2f(v[u].y);
                acc.z += wv[u] * bf2f(v[u].z);
                acc.w += wv[u] * bf2f(v[u].w);
            }
        }
        for (; i < deg; ++i) {
            float wv = __shfl(coef, i);
            int si = __shfl(s, i);
            const short4 hv = *(const short4*)(hbuf + (size_t)si * (H * DC) + hoff);
            acc.x += wv * bf2f(hv.x); acc.y += wv * bf2f(hv.y);
            acc.z += wv * bf2f(hv.z); acc.w += wv * bf2f(hv.w);
        }
    } else {
        float m = -1e38f;
        for (int i = beg + lane; i < end; i += 64) {
            int s = csr_src[i];
            m = fmaxf(m, lrelu02(asrc[s * H + hh] + ad));
        }
#pragma unroll
        for (int off = 32; off > 0; off >>= 1) m = fmaxf(m, __shfl_xor(m, off));
        float dsum = 0.f;
        for (int i = beg + lane; i < end; i += 64) {
            int s = csr_src[i];
            dsum += __expf(lrelu02(asrc[s * H + hh] + ad) - m);
        }
#pragma unroll
        for (int off = 32; off > 0; off >>= 1) dsum += __shfl_xor(dsum, off);
        float inv = 1.f / (dsum + 1e-16f);
        for (int i = beg; i < end; ++i) {
            int s = csr_src[i];
            float wv = __expf(lrelu02(asrc[s * H + hh] + ad) - m) * inv;
            const short4 hv = *(const short4*)(hbuf + ((size_t)s * H + hh) * DC + lane * 4);
            acc.x += wv * bf2f(hv.x); acc.y += wv * bf2f(hv.y);
            acc.z += wv * bf2f(hv.z); acc.w += wv * bf2f(hv.w);
        }
    }
    // ELU + bf16
    acc.x = acc.x > 0.f ? acc.x : __expf(acc.x) - 1.f;
    acc.y = acc.y > 0.f ? acc.y : __expf(acc.y) - 1.f;
    acc.z = acc.z > 0.f ? acc.z : __expf(acc.z) - 1.f;
    acc.w = acc.w > 0.f ? acc.w : __expf(acc.w) - 1.f;
    short4 o;
    o.x = f2bf(acc.x); o.y = f2bf(acc.y); o.z = f2bf(acc.z); o.w = f2bf(acc.w);
    *(short4*)(outx + cbase) = o;
}

// ---------------- Layer-3 aggregation: one block (6 waves) per node ---------------
// wave w handles head w: softmax (register path) + payload (8B/lane/edge, unroll 8);
// LDS reduction sums heads, adds preloaded lin3 row (in out), stores d_out[N,256].
__global__ __launch_bounds__(384) void gat_agg_mean(
    const short* __restrict__ hbuf, const float* __restrict__ asrc,
    const float* __restrict__ adst_a, const int* __restrict__ row_off,
    const int* __restrict__ csr_src, float* __restrict__ out, int N) {
    const int H = 6;
    __shared__ float red[6][DC];
    int n = blockIdx.x;
    int wave = threadIdx.x >> 6, lane = threadIdx.x & 63;
    int hh = wave;
    int beg = row_off[n], end = row_off[n + 1];
    int deg = end - beg;
    const float invH = 1.f / 6.f;
    float ad = adst_a[n * H + hh];

    float4 acc = make_float4(0.f, 0.f, 0.f, 0.f);
    const size_t hoff = (size_t)hh * DC + lane * 4;

    if (deg <= 64) {
        int s = 0; float e = -1e38f;
        if (lane < deg) {
            s = csr_src[beg + lane];
            e = lrelu02(asrc[s * H + hh] + ad);
        }
        float m = e;
#pragma unroll
        for (int off = 32; off > 0; off >>= 1) m = fmaxf(m, __shfl_xor(m, off));
        float p = (lane < deg) ? __expf(e - m) : 0.f;
        float dsum = p;
#pragma unroll
        for (int off = 32; off > 0; off >>= 1) dsum += __shfl_xor(dsum, off);
        float coef = p * invH / (dsum + 1e-16f);

        int i = 0;
        for (; i + 8 <= deg; i += 8) {
            short4 v[8]; float wv[8];
#pragma unroll
            for (int u = 0; u < 8; ++u) {
                int su = __shfl(s, i + u);
                v[u] = *(const short4*)(hbuf + (size_t)su * (H * DC) + hoff);
                wv[u] = __shfl(coef, i + u);
            }
#pragma unroll
            for (int u = 0; u < 8; ++u) {
                acc.x += wv[u] * bf2f(v[u].x);
                acc.y += wv[u] * bf2f(v[u].y);
                acc.z += wv[u] * bf2f(v[u].z);
                acc.w += wv[u] * bf2f(v[u].w);
            }
        }
        for (; i < deg; ++i) {
            float wv = __shfl(coef, i);
            int si = __shfl(s, i);
            const short4 hv = *(const short4*)(hbuf + (size_t)si * (H * DC) + hoff);
            acc.x += wv * bf2f(hv.x); acc.y += wv * bf2f(hv.y);
            acc.z += wv * bf2f(hv.z); acc.w += wv * bf2f(hv.w);
        }
    } else {
        float m = -1e38f;
        for (int i = beg + lane; i < end; i += 64) {
            int s = csr_src[i];
            m = fmaxf(m, lrelu02(asrc[s * H + hh] + ad));
        }
#pragma unroll
        for (int off = 32; off > 0; off >>= 1) m = fmaxf(m, __shfl_xor(m, off));
        float dsum = 0.f;
        for (int i = beg + lane; i < end; i += 64) {
            int s = csr_src[i];
            dsum += __expf(lrelu02(asrc[s * H + hh] + ad) - m);
        }
#pragma unroll
        for (int off = 32; off > 0; off >>= 1) dsum += __shfl_xor(dsum, off);
        float inv = invH / (dsum + 1e-16f);
        for (int i = beg; i < end; ++i) {
            int s = csr_src[i];
            float wv = __expf(lrelu02(asrc[s * H + hh] + ad) - m) * inv;
            const short4 hv = *(const short4*)(hbuf + (size_t)s * (H * DC) + hoff);
            acc.x += wv * bf2f(hv.x); acc.y += wv * bf2f(hv.y);
            acc.z += wv * bf2f(hv.z); acc.w += wv * bf2f(hv.w);
        }
    }
    *(float4*)&red[wave][lane * 4] = acc;
    __syncthreads();
    if (wave == 0) {
        float* op = out + (size_t)n * DC + lane * 4;
        float4 o = *(float4*)op;   // lin3 + b3 + lb3 preloaded by GEMM
#pragma unroll
        for (int j = 0; j < 6; ++j) {
            float4 r = *(float4*)&red[j][lane * 4];
            o.x += r.x; o.y += r.y; o.z += r.z; o.w += r.w;
        }
        *(float4*)op = o;
    }
}

// ---------------- launch ----------------
extern "C" void kernel_launch(void* const* d_in, const int* in_sizes, int n_in,
                              void* d_out, int out_size, void* d_ws, size_t ws_size,
                              hipStream_t stream) {
    const float* x   = (const float*)d_in[0];
    const int*   ei  = (const int*)d_in[1];
    const float* W1  = (const float*)d_in[2];
    const float* a1s = (const float*)d_in[3];
    const float* a1d = (const float*)d_in[4];
    const float* b1  = (const float*)d_in[5];
    const float* lw1 = (const float*)d_in[6];
    const float* lb1 = (const float*)d_in[7];
    const float* W2  = (const float*)d_in[8];
    const float* a2s = (const float*)d_in[9];
    const float* a2d = (const float*)d_in[10];
    const float* b2  = (const float*)d_in[11];
    const float* lb2_w = (const float*)d_in[12];
    const float* lb2 = (const float*)d_in[13];
    const float* W3  = (const float*)d_in[14];
    const float* a3s = (const float*)d_in[15];
    const float* a3d = (const float*)d_in[16];
    const float* b3  = (const float*)d_in[17];
    const float* lw3 = (const float*)d_in[18];
    const float* lb3 = (const float*)d_in[19];
    const float* lw2 = lb2_w;
    float* out = (float*)d_out;

    const int N = NN, E0 = EE0, E = EE0 + NN;

    unsigned char* w = (unsigned char*)d_ws;
    size_t off = 0;
    auto alloc = [&](size_t bytes) {
        void* p = w + off;
        off += (bytes + 255) & ~(size_t)255;
        return p;
    };
    short* hbuf   = (short*)alloc((size_t)N * 1536 * 2);  // h bf16 (max: layer 3)
    float* buf    = (float*)alloc((size_t)N * 1024 * 4);  // lin1, then lin2 (fp32)
    short* xb     = (short*)alloc((size_t)N * 1024 * 2);  // x1 bf16, then x2 bf16
    short* xpad   = (short*)alloc((size_t)N * 32 * 2);    // x zero-padded K=32 bf16
    short* W1p    = (short*)alloc((size_t)1024 * 32 * 2);       // + lw1p right after
    short* lw1p   = (short*)alloc((size_t)1024 * 32 * 2);
    short* W2b    = (short*)alloc((size_t)1024 * 1024 * 2);     // + lw2b right after
    short* lw2b   = (short*)alloc((size_t)1024 * 1024 * 2);
    short* W3b    = (short*)alloc((size_t)1536 * 1024 * 2);     // + lw3b right after
    short* lw3b   = (short*)alloc((size_t)256 * 1024 * 2);
    float* asrc   = (float*)alloc((size_t)N * 6 * 4);
    float* adst   = (float*)alloc((size_t)N * 6 * 4);
    int* row_off  = (int*)alloc((size_t)(N + 1) * 4);
    int* counts2  = (int*)alloc((size_t)2 * N * 4);  // counts | cursor
    int* counts   = counts2;
    int* cursor   = counts2 + N;
    int* csr_src  = (int*)alloc((size_t)E * 4);
    (void)ws_size; (void)n_in; (void)in_sizes; (void)out_size;

    // ---- CSR build ----
    hipMemsetAsync(counts2, 0, (size_t)2 * N * 4, stream);
    count_edges_k<<<ceildiv(E, 256), 256, 0, stream>>>(ei, counts, E0, N);
    scan_k<<<1, 1024, 0, stream>>>(counts, row_off, N);
    scatter_k<<<ceildiv(E, 256), 256, 0, stream>>>(ei, row_off, cursor, csr_src, E0, N);

    // ---- weight bf16 conversion (fused) + K-pad for layer 1 ----
    {
        int q0 = 1024 * 1024 / 4, q1 = 1024 * 1024 / 4, q2 = 1536 * 1024 / 4,
            q3 = 256 * 1024 / 4;
        cvt_bf16_fused_k<<<ceildiv(q0 + q1 + q2 + q3, 256), 256, 0, stream>>>(
            W2, W2b, q0, lw2, lw2b, q1, W3, W3b, q2, lw3, lw3b, q3);
        int rows = N + 1024 + 1024;
        pad_bf16_k<<<ceildiv(rows * 32, 256), 256, 0, stream>>>(
            x, xpad, N, W1, W1p, 1024, lw1, lw1p, 1024, NF, 32);
    }

    // ---- Layer 1 (H=4, K=14 padded to 32): h->hbuf bf16, lin->buf fp32 ----
    gemm_bf16_dual<<<dim3(16, ceildiv(N, 128)), 256, 0, stream>>>(
        xpad, W1p, b1, lb1, hbuf, buf, N, 1024, 1024, 32);
    alpha_k<<<ceildiv(N * 4, 4), 256, 0, stream>>>(hbuf, a1s, a1d, asrc, adst, N, 4);
    gat_agg<<<ceildiv(N * 4, 4), 256, 0, stream>>>(hbuf, buf, asrc, adst, row_off, csr_src,
                                                   xb, N, 4);

    // ---- Layer 2 (H=4, K=1024) ----
    gemm_bf16_dual<<<dim3(16, ceildiv(N, 128)), 256, 0, stream>>>(
        xb, W2b, b2, lb2, hbuf, buf, N, 1024, 1024, 1024);
    alpha_k<<<ceildiv(N * 4, 4), 256, 0, stream>>>(hbuf, a2s, a2d, asrc, adst, N, 4);
    gat_agg<<<ceildiv(N * 4, 4), 256, 0, stream>>>(hbuf, buf, asrc, adst, row_off, csr_src,
                                                   xb, N, 4);

    // ---- Layer 3 (H=6, K=1024, mean heads): h->hbuf, lin->out fp32 ----
    gemm_bf16_dual<<<dim3(14, ceildiv(N, 128)), 256, 0, stream>>>(
        xb, W3b, b3, lb3, hbuf, out, N, 1536, 256, 1024);
    alpha_k<<<ceildiv(N * 6, 4), 256, 0, stream>>>(hbuf, a3s, a3d, asrc, adst, N, 6);
    gat_agg_mean<<<N, 384, 0, stream>>>(hbuf, asrc, adst, row_off, csr_src, out, N);
}